// Round 5
// baseline (13462.357 us; speedup 1.0000x reference)
//
#include <hip/hip_runtime.h>
#include <hip/hip_bf16.h>

typedef __hip_bfloat16 bf16;

#define BATCH 16
#define HH 512
#define WW 512
#define HWSZ (HH * WW)
#define NCHN 16
// Conv passes run CHUNK batches at a time to keep workspace small
// (ws budget unknown; full-batch activations would need 319 MB and
// the Round-4 SIGABRT is consistent with a d_ws overflow fault).
#define CHUNK 1

// ---------------------------------------------------------------------------
// Block-wide sum reduction (256 threads = 4 waves of 64)
// ---------------------------------------------------------------------------
__device__ __forceinline__ float blockSum(float v) {
#pragma unroll
    for (int o = 32; o > 0; o >>= 1) v += __shfl_down(v, o, 64);
    __shared__ float sh[4];
    const int lane = threadIdx.x & 63, wid = threadIdx.x >> 6;
    if (lane == 0) sh[wid] = v;
    __syncthreads();
    float r = 0.f;
    if (threadIdx.x == 0) r = sh[0] + sh[1] + sh[2] + sh[3];
    __syncthreads();
    return r;
}

// ---------------------------------------------------------------------------
// Layer 0: Cin=2 (two fp32 planes w/ batch strides), Cout=16, leaky, bf16 out
// ---------------------------------------------------------------------------
__global__ __launch_bounds__(256) void k_conv_first(
    const float* __restrict__ p0, long long s0,
    const float* __restrict__ p1, long long s1,
    bf16* __restrict__ out,
    const float* __restrict__ w, const float* __restrict__ bias)
{
    const int tid = threadIdx.x;
    const int tx = tid & 31, ty = tid >> 5;
    const int bx0 = blockIdx.x * 32, by0 = blockIdx.y * 8, b = blockIdx.z;

    __shared__ float s_in[2][10][34];
    const float* pb0 = p0 + (long long)b * s0;
    const float* pb1 = p1 + (long long)b * s1;
    for (int idx = tid; idx < 2 * 10 * 34; idx += 256) {
        int ci = idx / 340, rem = idx - ci * 340;
        int yy = rem / 34, xx = rem - yy * 34;
        int gy = by0 + yy - 1, gx = bx0 + xx - 1;
        float v = 0.f;
        if ((unsigned)gy < HH && (unsigned)gx < WW) {
            const float* sp = ci ? pb1 : pb0;
            v = sp[gy * WW + gx];
        }
        s_in[ci][yy][xx] = v;
    }
    __syncthreads();

    float acc[16];
#pragma unroll
    for (int co = 0; co < 16; ++co) acc[co] = bias[co];

#pragma unroll
    for (int ci = 0; ci < 2; ++ci) {
        float v[9];
#pragma unroll
        for (int ky = 0; ky < 3; ++ky)
#pragma unroll
            for (int kx = 0; kx < 3; ++kx)
                v[ky * 3 + kx] = s_in[ci][ty + ky][tx + kx];
#pragma unroll
        for (int co = 0; co < 16; ++co) {
            const float* wp = w + (co * 2 + ci) * 9;
            float a = acc[co];
#pragma unroll
            for (int k = 0; k < 9; ++k) a = fmaf(v[k], wp[k], a);
            acc[co] = a;
        }
    }

    bf16* outb = out + (long long)b * NCHN * HWSZ + (by0 + ty) * WW + (bx0 + tx);
#pragma unroll
    for (int co = 0; co < 16; ++co) {
        float r = acc[co];
        r = (r >= 0.f) ? r : 0.01f * r;
        outb[(long long)co * HWSZ] = __float2bfloat16(r);
    }
}

// ---------------------------------------------------------------------------
// Middle layers: Cin=16 bf16, Cout=16, leaky, bf16 out
// ---------------------------------------------------------------------------
__global__ __launch_bounds__(256) void k_conv16(
    const bf16* __restrict__ in, bf16* __restrict__ out,
    const float* __restrict__ w, const float* __restrict__ bias)
{
    const int tid = threadIdx.x;
    const int tx = tid & 31, ty = tid >> 5;
    const int bx0 = blockIdx.x * 32, by0 = blockIdx.y * 8, b = blockIdx.z;

    __shared__ float s_in[NCHN][10][34];
    const bf16* inb = in + (long long)b * NCHN * HWSZ;
    for (int idx = tid; idx < NCHN * 10 * 34; idx += 256) {
        int ci = idx / 340, rem = idx - ci * 340;
        int yy = rem / 34, xx = rem - yy * 34;
        int gy = by0 + yy - 1, gx = bx0 + xx - 1;
        float v = 0.f;
        if ((unsigned)gy < HH && (unsigned)gx < WW)
            v = __bfloat162float(inb[(long long)ci * HWSZ + gy * WW + gx]);
        s_in[ci][yy][xx] = v;
    }
    __syncthreads();

    float acc[16];
#pragma unroll
    for (int co = 0; co < 16; ++co) acc[co] = bias[co];

#pragma unroll
    for (int ci = 0; ci < 16; ++ci) {
        float v[9];
#pragma unroll
        for (int ky = 0; ky < 3; ++ky)
#pragma unroll
            for (int kx = 0; kx < 3; ++kx)
                v[ky * 3 + kx] = s_in[ci][ty + ky][tx + kx];
#pragma unroll
        for (int co = 0; co < 16; ++co) {
            const float* wp = w + (co * 16 + ci) * 9;
            float a = acc[co];
#pragma unroll
            for (int k = 0; k < 9; ++k) a = fmaf(v[k], wp[k], a);
            acc[co] = a;
        }
    }

    bf16* outb = out + (long long)b * NCHN * HWSZ + (by0 + ty) * WW + (bx0 + tx);
#pragma unroll
    for (int co = 0; co < 16; ++co) {
        float r = acc[co];
        r = (r >= 0.f) ? r : 0.01f * r;
        outb[(long long)co * HWSZ] = __float2bfloat16(r);
    }
}

// ---------------------------------------------------------------------------
// Last layer: Cin=16 bf16, Cout=3, clip [-1,1], median3, out = xsrc - med
// ---------------------------------------------------------------------------
__global__ __launch_bounds__(256) void k_conv_last(
    const bf16* __restrict__ in,
    const float* __restrict__ xsrc, long long xstride,
    float* __restrict__ outp,
    const float* __restrict__ w, const float* __restrict__ bias)
{
    const int tid = threadIdx.x;
    const int tx = tid & 31, ty = tid >> 5;
    const int bx0 = blockIdx.x * 32, by0 = blockIdx.y * 8, b = blockIdx.z;

    __shared__ float s_in[NCHN][10][34];
    const bf16* inb = in + (long long)b * NCHN * HWSZ;
    for (int idx = tid; idx < NCHN * 10 * 34; idx += 256) {
        int ci = idx / 340, rem = idx - ci * 340;
        int yy = rem / 34, xx = rem - yy * 34;
        int gy = by0 + yy - 1, gx = bx0 + xx - 1;
        float v = 0.f;
        if ((unsigned)gy < HH && (unsigned)gx < WW)
            v = __bfloat162float(inb[(long long)ci * HWSZ + gy * WW + gx]);
        s_in[ci][yy][xx] = v;
    }
    __syncthreads();

    float acc[3] = { bias[0], bias[1], bias[2] };

#pragma unroll
    for (int ci = 0; ci < 16; ++ci) {
        float v[9];
#pragma unroll
        for (int ky = 0; ky < 3; ++ky)
#pragma unroll
            for (int kx = 0; kx < 3; ++kx)
                v[ky * 3 + kx] = s_in[ci][ty + ky][tx + kx];
#pragma unroll
        for (int co = 0; co < 3; ++co) {
            const float* wp = w + (co * 16 + ci) * 9;
            float a = acc[co];
#pragma unroll
            for (int k = 0; k < 9; ++k) a = fmaf(v[k], wp[k], a);
            acc[co] = a;
        }
    }

    float y0 = fminf(fmaxf(acc[0], -1.f), 1.f);
    float y1 = fminf(fmaxf(acc[1], -1.f), 1.f);
    float y2 = fminf(fmaxf(acc[2], -1.f), 1.f);
    // median3(a,b,c) = max(min(a, max(b,c)), min(b,c))
    float med = fmaxf(fminf(y0, fmaxf(y1, y2)), fminf(y1, y2));

    const int gy = by0 + ty, gx = bx0 + tx;
    const long long pix = (long long)gy * WW + gx;
    outp[(long long)b * HWSZ + pix] = xsrc[(long long)b * xstride + pix] - med;
}

// ---------------------------------------------------------------------------
// Stats over x: sum of squares + per-(b,c) 256-bin histogram
// grid: (64, 48)  -- blockIdx.y = b*3+c (x is contiguous (B,3,H,W))
// ---------------------------------------------------------------------------
__global__ __launch_bounds__(256) void k_stats_x(
    const float* __restrict__ x, unsigned* __restrict__ hist, float* __restrict__ sums)
{
    const int p = blockIdx.y;
    const float* src = x + (long long)p * HWSZ;
    __shared__ unsigned h[256];
    h[threadIdx.x] = 0;
    __syncthreads();

    float ss = 0.f;
    for (int i = blockIdx.x * 256 + threadIdx.x; i < HWSZ; i += gridDim.x * 256) {
        float v = src[i];
        ss += v * v;
        if (v >= -1.f && v <= 1.f) {
            int idx = (int)floorf((v + 1.f) * 128.f);
            idx = min(max(idx, 0), 255);
            atomicAdd(&h[idx], 1u);
        }
    }
    __syncthreads();
    if (h[threadIdx.x]) atomicAdd(&hist[p * 256 + threadIdx.x], h[threadIdx.x]);

    float bs = blockSum(ss);
    if (threadIdx.x == 0) atomicAdd(&sums[0], bs);
}

// ---------------------------------------------------------------------------
// Stats over deltas of one plane (channel c): delta = v - clampgrad_pred
// grid: (64, 16)  -- blockIdx.y = b ; hist row = b*3 + c
// ---------------------------------------------------------------------------
__global__ __launch_bounds__(256) void k_stats_delta(
    const float* __restrict__ plane, int c,
    unsigned* __restrict__ hist, float* __restrict__ sums)
{
    const int b = blockIdx.y;
    const float* P = plane + (long long)b * HWSZ;
    const int row = b * 3 + c;
    __shared__ unsigned h[256];
    h[threadIdx.x] = 0;
    __syncthreads();

    float ss = 0.f;
    for (int i = blockIdx.x * 256 + threadIdx.x; i < HWSZ; i += gridDim.x * 256) {
        const int y = i >> 9, x = i & (WW - 1);
        float v = P[i];
        float n  = y ? P[i - WW] : 0.f;
        float wv = x ? P[i - 1] : 0.f;
        float nw = (y && x) ? P[i - WW - 1] : 0.f;
        float pr = n + wv - nw;
        pr = fminf(fmaxf(pr, fminf(n, wv)), fmaxf(n, wv));
        float d = v - pr;
        ss += d * d;
        if (d >= -1.f && d <= 1.f) {
            int idx = (int)floorf((d + 1.f) * 128.f);
            idx = min(max(idx, 0), 255);
            atomicAdd(&h[idx], 1u);
        }
    }
    __syncthreads();
    if (h[threadIdx.x]) atomicAdd(&hist[row * 256 + threadIdx.x], h[threadIdx.x]);

    float bs = blockSum(ss);
    if (threadIdx.x == 0) atomicAdd(&sums[1], bs);
}

// ---------------------------------------------------------------------------
// Finalize: entropies + the 4 output scalars
// ---------------------------------------------------------------------------
__global__ __launch_bounds__(256) void k_finalize(
    const unsigned* __restrict__ hist0, const unsigned* __restrict__ hist1,
    const float* __restrict__ sums, float* __restrict__ out)
{
    float e0 = 0.f, e1 = 0.f;
    for (int i = threadIdx.x; i < 48 * 256; i += 256) {
        float p0 = (float)hist0[i] * (1.0f / HWSZ);
        if (p0 > 0.f) e0 -= p0 * log2f(p0);
        float p1 = (float)hist1[i] * (1.0f / HWSZ);
        if (p1 > 0.f) e1 -= p1 * log2f(p1);
    }
    float t0 = blockSum(e0);
    float t1 = blockSum(e1);
    if (threadIdx.x == 0) {
        const float N = (float)BATCH * 3.f * (float)HWSZ;
        out[0] = 128.f * sqrtf(sums[1] / N);   // loss1 (deltas)
        out[1] = 128.f * sqrtf(sums[0] / N);   // loss0 (x)
        out[2] = t0 * (1.f / (8.f * 48.f));    // invcr0
        out[3] = t1 * (1.f / (8.f * 48.f));    // invcr1
    }
}

// ---------------------------------------------------------------------------
extern "C" void kernel_launch(void* const* d_in, const int* in_sizes, int n_in,
                              void* d_out, int out_size, void* d_ws, size_t ws_size,
                              hipStream_t stream) {
    const float* x = (const float*)d_in[0];
    const float* w[8];
    const float* bs[8];
    for (int i = 0; i < 8; ++i) {
        w[i]  = (const float*)d_in[1 + 2 * i];
        bs[i] = (const float*)d_in[2 + 2 * i];
    }

    // Workspace (~67 MB total; CHUNK=1 keeps activations at 2 x 8.4 MB)
    char* ws = (char*)d_ws;
    size_t o = 0;
    bf16* actA = (bf16*)(ws + o); o += (size_t)CHUNK * NCHN * HWSZ * 2;
    bf16* actB = (bf16*)(ws + o); o += (size_t)CHUNK * NCHN * HWSZ * 2;
    float* rpl = (float*)(ws + o); o += (size_t)BATCH * HWSZ * 4;
    float* gpl = (float*)(ws + o); o += (size_t)BATCH * HWSZ * 4;
    float* bpl = (float*)(ws + o); o += (size_t)BATCH * HWSZ * 4;
    unsigned* hist0 = (unsigned*)(ws + o); o += 48 * 256 * 4;
    unsigned* hist1 = (unsigned*)(ws + o); o += 48 * 256 * 4;
    float* sums = (float*)(ws + o); o += 256;

    // zero hist0 + hist1 + sums (contiguous)
    hipMemsetAsync(hist0, 0, 48 * 256 * 4 * 2 + 256, stream);

    const dim3 cgrid(WW / 32, HH / 8, CHUNK);
    const dim3 cblk(256);

    auto predictor = [&](const float* pa, long long sa, const float* pb, long long sb,
                         float* outp, int c) {
        for (int b0 = 0; b0 < BATCH; b0 += CHUNK) {
            k_conv_first<<<cgrid, cblk, 0, stream>>>(pa + (long long)b0 * sa, sa,
                                                     pb + (long long)b0 * sb, sb,
                                                     actA, w[0], bs[0]);
            k_conv16<<<cgrid, cblk, 0, stream>>>(actA, actB, w[1], bs[1]);
            k_conv16<<<cgrid, cblk, 0, stream>>>(actB, actA, w[2], bs[2]);
            k_conv16<<<cgrid, cblk, 0, stream>>>(actA, actB, w[3], bs[3]);
            k_conv16<<<cgrid, cblk, 0, stream>>>(actB, actA, w[4], bs[4]);
            k_conv16<<<cgrid, cblk, 0, stream>>>(actA, actB, w[5], bs[5]);
            k_conv16<<<cgrid, cblk, 0, stream>>>(actB, actA, w[6], bs[6]);
            k_conv_last<<<cgrid, cblk, 0, stream>>>(
                actA,
                x + (long long)c * HWSZ + (long long)b0 * 3 * HWSZ, 3LL * HWSZ,
                outp + (long long)b0 * HWSZ, w[7], bs[7]);
        }
    };

    // r = x_r - pred(g, b);  g = x_g - pred(r, b);  b = x_b - pred(r, g)
    predictor(x + 1LL * HWSZ, 3LL * HWSZ, x + 2LL * HWSZ, 3LL * HWSZ, rpl, 0);
    predictor(rpl, (long long)HWSZ, x + 2LL * HWSZ, 3LL * HWSZ, gpl, 1);
    predictor(rpl, (long long)HWSZ, gpl, (long long)HWSZ, bpl, 2);

    const dim3 sgrid(64, 48);
    k_stats_x<<<sgrid, 256, 0, stream>>>(x, hist0, sums);
    const dim3 dgrid(64, BATCH);
    k_stats_delta<<<dgrid, 256, 0, stream>>>(rpl, 0, hist1, sums);
    k_stats_delta<<<dgrid, 256, 0, stream>>>(gpl, 1, hist1, sums);
    k_stats_delta<<<dgrid, 256, 0, stream>>>(bpl, 2, hist1, sums);

    k_finalize<<<1, 256, 0, stream>>>(hist0, hist1, sums, (float*)d_out);
}

// Round 6
// 3998.265 us; speedup vs baseline: 3.3670x; 3.3670x over previous
//
#include <hip/hip_runtime.h>
#include <hip/hip_bf16.h>

typedef __hip_bfloat16 hbf16;
typedef __attribute__((ext_vector_type(8))) short bfrag8;
typedef __attribute__((ext_vector_type(4))) short short4v;
typedef __attribute__((ext_vector_type(4))) float f32x4;

#define BATCH 16
#define HH 512
#define WW 512
#define HWSZ (HH * WW)
#define NCHN 16
// MFMA conv tile: 64 px wide (4 waves x 16), 8 rows
#define TLX 64
#define TLY 8
#define H2 (TLY + 2)
#define W2 (TLX + 2)

__device__ __forceinline__ float bf2f(short s) {
    union { unsigned u; float f; } c;
    c.u = ((unsigned)(unsigned short)s) << 16;
    return c.f;
}
__device__ __forceinline__ short f2bf(float f) {
    hbf16 h = __float2bfloat16(f);
    return *(short*)&h;
}

// ---------------------------------------------------------------------------
// Block-wide sum reduction (256 threads = 4 waves of 64)
// ---------------------------------------------------------------------------
__device__ __forceinline__ float blockSum(float v) {
#pragma unroll
    for (int o = 32; o > 0; o >>= 1) v += __shfl_down(v, o, 64);
    __shared__ float sh[4];
    const int lane = threadIdx.x & 63, wid = threadIdx.x >> 6;
    if (lane == 0) sh[wid] = v;
    __syncthreads();
    float r = 0.f;
    if (threadIdx.x == 0) r = sh[0] + sh[1] + sh[2] + sh[3];
    __syncthreads();
    return r;
}

// ---------------------------------------------------------------------------
// Layer 0: Cin=2 (two fp32 planes w/ batch strides), Cout=16, leaky,
// bf16 NHWC output [y][x][16ci]
// ---------------------------------------------------------------------------
__global__ __launch_bounds__(256) void k_conv_first(
    const float* __restrict__ p0, long long s0,
    const float* __restrict__ p1, long long s1,
    short* __restrict__ out,
    const float* __restrict__ w, const float* __restrict__ bias)
{
    const int tid = threadIdx.x;
    const int tx = tid & 31, ty = tid >> 5;
    const int bx0 = blockIdx.x * 32, by0 = blockIdx.y * 8;

    __shared__ float s_in[2][10][34];
    const float* pb0 = p0 + (long long)blockIdx.z * s0;
    const float* pb1 = p1 + (long long)blockIdx.z * s1;
    for (int idx = tid; idx < 2 * 10 * 34; idx += 256) {
        int ci = idx / 340, rem = idx - ci * 340;
        int yy = rem / 34, xx = rem - yy * 34;
        int gy = by0 + yy - 1, gx = bx0 + xx - 1;
        float v = 0.f;
        if ((unsigned)gy < HH && (unsigned)gx < WW)
            v = (ci ? pb1 : pb0)[gy * WW + gx];
        s_in[ci][yy][xx] = v;
    }
    __syncthreads();

    float acc[16];
#pragma unroll
    for (int co = 0; co < 16; ++co) acc[co] = bias[co];

#pragma unroll
    for (int ci = 0; ci < 2; ++ci) {
        float v[9];
#pragma unroll
        for (int ky = 0; ky < 3; ++ky)
#pragma unroll
            for (int kx = 0; kx < 3; ++kx)
                v[ky * 3 + kx] = s_in[ci][ty + ky][tx + kx];
#pragma unroll
        for (int co = 0; co < 16; ++co) {
            const float* wp = w + (co * 2 + ci) * 9;
            float a = acc[co];
#pragma unroll
            for (int k = 0; k < 9; ++k) a = fmaf(v[k], wp[k], a);
            acc[co] = a;
        }
    }

    short* op = out + (long long)blockIdx.z * NCHN * HWSZ
                    + ((long long)(by0 + ty) * WW + (bx0 + tx)) * 16;
    bfrag8 pk0, pk1;
#pragma unroll
    for (int co = 0; co < 8; ++co) {
        float r = acc[co];
        pk0[co] = f2bf(r >= 0.f ? r : 0.01f * r);
    }
#pragma unroll
    for (int co = 0; co < 8; ++co) {
        float r = acc[co + 8];
        pk1[co] = f2bf(r >= 0.f ? r : 0.01f * r);
    }
    *(bfrag8*)op = pk0;
    *(bfrag8*)(op + 8) = pk1;
}

// ---------------------------------------------------------------------------
// Middle layers via MFMA implicit GEMM.
// GEMM: D[cout=16][px=16] += A[16][K=160] * B[K=160][16], K = koff*16 + ci
// (koff 0..8 = 3x3 tap, padded to 10; pad taps have zero A).
// A-frag (lane l, kstep s): row=l&15 (cout), k=(l>>4)*8+j+32s.
// B-frag (lane l, kstep s): col=l&15 (pixel), same k slice -> 8 consecutive
// ci at one tap/pixel = one ds_read_b128 from NHWC LDS tile.
// C/D: col=lane&15 (pixel), row=(lane>>4)*4+i (cout)  [m89-verified mapping]
// ---------------------------------------------------------------------------
__global__ __launch_bounds__(256) void k_conv16_mfma(
    const short* __restrict__ in, short* __restrict__ out,
    const float* __restrict__ w, const float* __restrict__ bias)
{
    __shared__ short s_tile[2][H2][W2][8];   // [ci half][y][x][8 ci] bf16
    const int tid = threadIdx.x;
    const int lane = tid & 63, wvid = tid >> 6;
    const int bx0 = blockIdx.x * TLX, by0 = blockIdx.y * TLY;
    const long long bofs = (long long)blockIdx.z * NCHN * HWSZ;
    const short* inb = in + bofs;

    // stage halo tile [by0-1 .. by0+TLY] x [bx0-1 .. bx0+TLX], NHWC
    for (int idx = tid; idx < H2 * W2 * 2; idx += 256) {
        int half = idx & 1, pix = idx >> 1;
        int yy = pix / W2, xx = pix - yy * W2;
        int gy = by0 + yy - 1, gx = bx0 + xx - 1;
        bfrag8 v = {0, 0, 0, 0, 0, 0, 0, 0};
        if ((unsigned)gy < HH && (unsigned)gx < WW)
            v = *(const bfrag8*)(inb + ((long long)gy * WW + gx) * 16 + half * 8);
        *(bfrag8*)(&s_tile[half][yy][xx][0]) = v;
    }

    // A fragments from weights (w layout [co][ci][ky][kx] fp32)
    const int arow = lane & 15;       // cout
    const int grp  = lane >> 4;       // 0..3
    const int half = grp & 1;         // ci block select
    const int cib  = half * 8;
    const int kofb = grp >> 1;        // 0/1 tap offset within kstep
    bfrag8 afrag[5];
#pragma unroll
    for (int s = 0; s < 5; ++s) {
        int koff = 2 * s + kofb;
#pragma unroll
        for (int j = 0; j < 8; ++j) {
            float wv = (koff < 9) ? w[(arow * 16 + cib + j) * 9 + koff] : 0.f;
            afrag[s][j] = f2bf(wv);
        }
    }
    const int c0 = grp * 4;           // C/D cout base
    const float bi0 = bias[c0], bi1 = bias[c0 + 1],
                bi2 = bias[c0 + 2], bi3 = bias[c0 + 3];

    __syncthreads();

    const int pxl = wvid * 16 + (lane & 15);  // local x 0..63
    const int gx = bx0 + pxl;
    short* outb = out + bofs;

    for (int yy = 0; yy < TLY; ++yy) {
        f32x4 acc = { bi0, bi1, bi2, bi3 };
#pragma unroll
        for (int s = 0; s < 5; ++s) {
            int koff = 2 * s + kofb;
            if (koff > 8) koff = 8;           // pad tap: A is zero anyway
            const int dy = koff / 3, dx = koff - dy * 3;   // 0..2
            const bfrag8 bfr = *(const bfrag8*)(&s_tile[half][yy + dy][pxl + dx][0]);
            acc = __builtin_amdgcn_mfma_f32_16x16x32_bf16(afrag[s], bfr, acc, 0, 0, 0);
        }
        short4v st;
#pragma unroll
        for (int i = 0; i < 4; ++i) {
            float r = acc[i];
            st[i] = f2bf(r >= 0.f ? r : 0.01f * r);
        }
        *(short4v*)(outb + ((long long)(by0 + yy) * WW + gx) * 16 + c0) = st;
    }
}

// ---------------------------------------------------------------------------
// Last layer: Cin=16 bf16 NHWC, Cout=3, clip [-1,1], median3, out=xsrc-med
// ---------------------------------------------------------------------------
__global__ __launch_bounds__(256) void k_conv_last(
    const short* __restrict__ in,
    const float* __restrict__ xsrc, long long xstride,
    float* __restrict__ outp,
    const float* __restrict__ w, const float* __restrict__ bias)
{
    const int tid = threadIdx.x;
    const int tx = tid & 31, ty = tid >> 5;
    const int bx0 = blockIdx.x * 32, by0 = blockIdx.y * 8;

    __shared__ short s_in[10][34][16];
    __shared__ float s_w[3 * 16 * 9];
    const short* inb = in + (long long)blockIdx.z * NCHN * HWSZ;
    for (int idx = tid; idx < 10 * 34 * 2; idx += 256) {
        int half = idx & 1, pix = idx >> 1;
        int yy = pix / 34, xx = pix - yy * 34;
        int gy = by0 + yy - 1, gx = bx0 + xx - 1;
        bfrag8 v = {0, 0, 0, 0, 0, 0, 0, 0};
        if ((unsigned)gy < HH && (unsigned)gx < WW)
            v = *(const bfrag8*)(inb + ((long long)gy * WW + gx) * 16 + half * 8);
        *(bfrag8*)(&s_in[yy][xx][half * 8]) = v;
    }
    for (int idx = tid; idx < 432; idx += 256) s_w[idx] = w[idx];
    __syncthreads();

    float a0 = bias[0], a1 = bias[1], a2 = bias[2];
#pragma unroll
    for (int ky = 0; ky < 3; ++ky)
#pragma unroll
    for (int kx = 0; kx < 3; ++kx) {
        const int koff = ky * 3 + kx;
        const short* sp = &s_in[ty + ky][tx + kx][0];
#pragma unroll
        for (int ci = 0; ci < 16; ++ci) {
            float xv = bf2f(sp[ci]);
            a0 = fmaf(xv, s_w[(0 * 16 + ci) * 9 + koff], a0);
            a1 = fmaf(xv, s_w[(1 * 16 + ci) * 9 + koff], a1);
            a2 = fmaf(xv, s_w[(2 * 16 + ci) * 9 + koff], a2);
        }
    }

    float y0 = fminf(fmaxf(a0, -1.f), 1.f);
    float y1 = fminf(fmaxf(a1, -1.f), 1.f);
    float y2 = fminf(fmaxf(a2, -1.f), 1.f);
    float med = fmaxf(fminf(y0, fmaxf(y1, y2)), fminf(y1, y2));

    const int gy = by0 + ty, gx = bx0 + tx;
    const long long pix = (long long)gy * WW + gx;
    outp[(long long)blockIdx.z * HWSZ + pix] =
        xsrc[(long long)blockIdx.z * xstride + pix] - med;
}

// ---------------------------------------------------------------------------
// Stats over x: sum of squares + per-(b,c) 256-bin histogram
// ---------------------------------------------------------------------------
__global__ __launch_bounds__(256) void k_stats_x(
    const float* __restrict__ x, unsigned* __restrict__ hist, float* __restrict__ sums)
{
    const int p = blockIdx.y;
    const float* src = x + (long long)p * HWSZ;
    __shared__ unsigned h[256];
    h[threadIdx.x] = 0;
    __syncthreads();

    float ss = 0.f;
    for (int i = blockIdx.x * 256 + threadIdx.x; i < HWSZ; i += gridDim.x * 256) {
        float v = src[i];
        ss += v * v;
        if (v >= -1.f && v <= 1.f) {
            int idx = (int)floorf((v + 1.f) * 128.f);
            idx = min(max(idx, 0), 255);
            atomicAdd(&h[idx], 1u);
        }
    }
    __syncthreads();
    if (h[threadIdx.x]) atomicAdd(&hist[p * 256 + threadIdx.x], h[threadIdx.x]);

    float bs = blockSum(ss);
    if (threadIdx.x == 0) atomicAdd(&sums[0], bs);
}

// ---------------------------------------------------------------------------
// Stats over deltas of one plane: delta = v - clampgrad_pred
// ---------------------------------------------------------------------------
__global__ __launch_bounds__(256) void k_stats_delta(
    const float* __restrict__ plane, int c,
    unsigned* __restrict__ hist, float* __restrict__ sums)
{
    const int b = blockIdx.y;
    const float* P = plane + (long long)b * HWSZ;
    const int row = b * 3 + c;
    __shared__ unsigned h[256];
    h[threadIdx.x] = 0;
    __syncthreads();

    float ss = 0.f;
    for (int i = blockIdx.x * 256 + threadIdx.x; i < HWSZ; i += gridDim.x * 256) {
        const int y = i >> 9, x = i & (WW - 1);
        float v = P[i];
        float n  = y ? P[i - WW] : 0.f;
        float wv = x ? P[i - 1] : 0.f;
        float nw = (y && x) ? P[i - WW - 1] : 0.f;
        float pr = n + wv - nw;
        pr = fminf(fmaxf(pr, fminf(n, wv)), fmaxf(n, wv));
        float d = v - pr;
        ss += d * d;
        if (d >= -1.f && d <= 1.f) {
            int idx = (int)floorf((d + 1.f) * 128.f);
            idx = min(max(idx, 0), 255);
            atomicAdd(&h[idx], 1u);
        }
    }
    __syncthreads();
    if (h[threadIdx.x]) atomicAdd(&hist[row * 256 + threadIdx.x], h[threadIdx.x]);

    float bs = blockSum(ss);
    if (threadIdx.x == 0) atomicAdd(&sums[1], bs);
}

// ---------------------------------------------------------------------------
// Finalize: entropies + the 4 output scalars
// ---------------------------------------------------------------------------
__global__ __launch_bounds__(256) void k_finalize(
    const unsigned* __restrict__ hist0, const unsigned* __restrict__ hist1,
    const float* __restrict__ sums, float* __restrict__ out)
{
    float e0 = 0.f, e1 = 0.f;
    for (int i = threadIdx.x; i < 48 * 256; i += 256) {
        float p0 = (float)hist0[i] * (1.0f / HWSZ);
        if (p0 > 0.f) e0 -= p0 * log2f(p0);
        float p1 = (float)hist1[i] * (1.0f / HWSZ);
        if (p1 > 0.f) e1 -= p1 * log2f(p1);
    }
    float t0 = blockSum(e0);
    float t1 = blockSum(e1);
    if (threadIdx.x == 0) {
        const float N = (float)BATCH * 3.f * (float)HWSZ;
        out[0] = 128.f * sqrtf(sums[1] / N);   // loss1 (deltas)
        out[1] = 128.f * sqrtf(sums[0] / N);   // loss0 (x)
        out[2] = t0 * (1.f / (8.f * 48.f));    // invcr0
        out[3] = t1 * (1.f / (8.f * 48.f));    // invcr1
    }
}

// ---------------------------------------------------------------------------
extern "C" void kernel_launch(void* const* d_in, const int* in_sizes, int n_in,
                              void* d_out, int out_size, void* d_ws, size_t ws_size,
                              hipStream_t stream) {
    const float* x = (const float*)d_in[0];
    const float* w[8];
    const float* bs[8];
    for (int i = 0; i < 8; ++i) {
        w[i]  = (const float*)d_in[1 + 2 * i];
        bs[i] = (const float*)d_in[2 + 2 * i];
    }

    // Fixed workspace first (planes + hists + sums ~ 50.4 MB), then
    // activation ping-pong sized adaptively from ws_size (deterministic).
    char* ws = (char*)d_ws;
    size_t o = 0;
    float* rpl = (float*)(ws + o); o += (size_t)BATCH * HWSZ * 4;
    float* gpl = (float*)(ws + o); o += (size_t)BATCH * HWSZ * 4;
    float* bpl = (float*)(ws + o); o += (size_t)BATCH * HWSZ * 4;
    unsigned* hist0 = (unsigned*)(ws + o); o += 48 * 256 * 4;
    unsigned* hist1 = (unsigned*)(ws + o); o += 48 * 256 * 4;
    float* sums = (float*)(ws + o); o += 256;

    const size_t actElems = (size_t)NCHN * HWSZ;        // per batch, shorts
    const size_t perBatchBytes = 2 * actElems * 2;      // A+B buffers
    int chunk = 1;
    if (ws_size > o) {
        size_t c = (ws_size - o) / perBatchBytes;
        chunk = (c < 1) ? 1 : (c > BATCH ? BATCH : (int)c);
    }
    short* actA = (short*)(ws + o);
    short* actB = actA + (size_t)chunk * actElems;

    hipMemsetAsync(hist0, 0, 48 * 256 * 4 * 2 + 256, stream);

    auto predictor = [&](const float* pa, long long sa, const float* pb, long long sb,
                         float* outp, int c) {
        for (int b0 = 0; b0 < BATCH; b0 += chunk) {
            const int zc = (BATCH - b0 < chunk) ? (BATCH - b0) : chunk;
            const dim3 g1(WW / 32, HH / 8, zc);
            const dim3 gm(WW / TLX, HH / TLY, zc);
            k_conv_first<<<g1, 256, 0, stream>>>(pa + (long long)b0 * sa, sa,
                                                 pb + (long long)b0 * sb, sb,
                                                 actA, w[0], bs[0]);
            k_conv16_mfma<<<gm, 256, 0, stream>>>(actA, actB, w[1], bs[1]);
            k_conv16_mfma<<<gm, 256, 0, stream>>>(actB, actA, w[2], bs[2]);
            k_conv16_mfma<<<gm, 256, 0, stream>>>(actA, actB, w[3], bs[3]);
            k_conv16_mfma<<<gm, 256, 0, stream>>>(actB, actA, w[4], bs[4]);
            k_conv16_mfma<<<gm, 256, 0, stream>>>(actA, actB, w[5], bs[5]);
            k_conv16_mfma<<<gm, 256, 0, stream>>>(actB, actA, w[6], bs[6]);
            k_conv_last<<<g1, 256, 0, stream>>>(
                actA,
                x + (long long)c * HWSZ + (long long)b0 * 3 * HWSZ, 3LL * HWSZ,
                outp + (long long)b0 * HWSZ, w[7], bs[7]);
        }
    };

    // r = x_r - pred(g, b);  g = x_g - pred(r, b);  b = x_b - pred(r, g)
    predictor(x + 1LL * HWSZ, 3LL * HWSZ, x + 2LL * HWSZ, 3LL * HWSZ, rpl, 0);
    predictor(rpl, (long long)HWSZ, x + 2LL * HWSZ, 3LL * HWSZ, gpl, 1);
    predictor(rpl, (long long)HWSZ, gpl, (long long)HWSZ, bpl, 2);

    const dim3 sgrid(64, 48);
    k_stats_x<<<sgrid, 256, 0, stream>>>(x, hist0, sums);
    const dim3 dgrid(64, BATCH);
    k_stats_delta<<<dgrid, 256, 0, stream>>>(rpl, 0, hist1, sums);
    k_stats_delta<<<dgrid, 256, 0, stream>>>(gpl, 1, hist1, sums);
    k_stats_delta<<<dgrid, 256, 0, stream>>>(bpl, 2, hist1, sums);

    k_finalize<<<1, 256, 0, stream>>>(hist0, hist1, sums, (float*)d_out);
}

// Round 7
// 3464.650 us; speedup vs baseline: 3.8856x; 1.1540x over previous
//
#include <hip/hip_runtime.h>
#include <hip/hip_bf16.h>

typedef __hip_bfloat16 hbf16;
typedef __attribute__((ext_vector_type(8))) short bfrag8;
typedef __attribute__((ext_vector_type(4))) short short4v;
typedef __attribute__((ext_vector_type(4))) float f32x4;

#define BATCH 16
#define HH 512
#define WW 512
#define HWSZ (HH * WW)
#define NCHN 16
// MFMA conv tile: 64 px wide (4 waves x 16), 8 rows
#define TLX 64
#define TLY 8
#define H2 (TLY + 2)
#define W2 (TLX + 2)

__device__ __forceinline__ float bf2f(short s) {
    union { unsigned u; float f; } c;
    c.u = ((unsigned)(unsigned short)s) << 16;
    return c.f;
}
__device__ __forceinline__ short f2bf(float f) {
    hbf16 h = __float2bfloat16(f);
    return *(short*)&h;
}

// ---------------------------------------------------------------------------
// Block-wide sum reduction (256 threads = 4 waves of 64)
// ---------------------------------------------------------------------------
__device__ __forceinline__ float blockSum(float v) {
#pragma unroll
    for (int o = 32; o > 0; o >>= 1) v += __shfl_down(v, o, 64);
    __shared__ float sh[4];
    const int lane = threadIdx.x & 63, wid = threadIdx.x >> 6;
    if (lane == 0) sh[wid] = v;
    __syncthreads();
    float r = 0.f;
    if (threadIdx.x == 0) r = sh[0] + sh[1] + sh[2] + sh[3];
    __syncthreads();
    return r;
}

// ---------------------------------------------------------------------------
// Layer 0: Cin=2 (two fp32 planes w/ batch strides), Cout=16, leaky,
// bf16 NHWC output [y][x][16ci]
// ---------------------------------------------------------------------------
__global__ __launch_bounds__(256) void k_conv_first(
    const float* __restrict__ p0, long long s0,
    const float* __restrict__ p1, long long s1,
    short* __restrict__ out,
    const float* __restrict__ w, const float* __restrict__ bias)
{
    const int tid = threadIdx.x;
    const int tx = tid & 31, ty = tid >> 5;
    const int bx0 = blockIdx.x * 32, by0 = blockIdx.y * 8;

    __shared__ float s_in[2][10][34];
    const float* pb0 = p0 + (long long)blockIdx.z * s0;
    const float* pb1 = p1 + (long long)blockIdx.z * s1;
    for (int idx = tid; idx < 2 * 10 * 34; idx += 256) {
        int ci = idx / 340, rem = idx - ci * 340;
        int yy = rem / 34, xx = rem - yy * 34;
        int gy = by0 + yy - 1, gx = bx0 + xx - 1;
        float v = 0.f;
        if ((unsigned)gy < HH && (unsigned)gx < WW)
            v = (ci ? pb1 : pb0)[gy * WW + gx];
        s_in[ci][yy][xx] = v;
    }
    __syncthreads();

    float acc[16];
#pragma unroll
    for (int co = 0; co < 16; ++co) acc[co] = bias[co];

#pragma unroll
    for (int ci = 0; ci < 2; ++ci) {
        float v[9];
#pragma unroll
        for (int ky = 0; ky < 3; ++ky)
#pragma unroll
            for (int kx = 0; kx < 3; ++kx)
                v[ky * 3 + kx] = s_in[ci][ty + ky][tx + kx];
#pragma unroll
        for (int co = 0; co < 16; ++co) {
            const float* wp = w + (co * 2 + ci) * 9;
            float a = acc[co];
#pragma unroll
            for (int k = 0; k < 9; ++k) a = fmaf(v[k], wp[k], a);
            acc[co] = a;
        }
    }

    short* op = out + (long long)blockIdx.z * NCHN * HWSZ
                    + ((long long)(by0 + ty) * WW + (bx0 + tx)) * 16;
    bfrag8 pk0, pk1;
#pragma unroll
    for (int co = 0; co < 8; ++co) {
        float r = acc[co];
        pk0[co] = f2bf(r >= 0.f ? r : 0.01f * r);
    }
#pragma unroll
    for (int co = 0; co < 8; ++co) {
        float r = acc[co + 8];
        pk1[co] = f2bf(r >= 0.f ? r : 0.01f * r);
    }
    *(bfrag8*)op = pk0;
    *(bfrag8*)(op + 8) = pk1;
}

// ---------------------------------------------------------------------------
// Middle layers via MFMA implicit GEMM.
// GEMM: D[cout=16][px=16] += A[16][K=160] * B[K=160][16], K = koff*16 + ci
// (koff 0..8 = 3x3 tap, padded to 10; pad taps have zero A).
// A-frag (lane l, kstep s): row=l&15 (cout), k=(l>>4)*8+j+32s.
// B-frag (lane l, kstep s): col=l&15 (pixel), same k slice -> 8 consecutive
// ci at one tap/pixel = one ds_read_b128 from NHWC LDS tile.
// C/D: col=lane&15 (pixel), row=(lane>>4)*4+i (cout)  [m89-verified mapping]
// ---------------------------------------------------------------------------
__global__ __launch_bounds__(256) void k_conv16_mfma(
    const short* __restrict__ in, short* __restrict__ out,
    const float* __restrict__ w, const float* __restrict__ bias)
{
    __shared__ short s_tile[2][H2][W2][8];   // [ci half][y][x][8 ci] bf16
    const int tid = threadIdx.x;
    const int lane = tid & 63, wvid = tid >> 6;
    const int bx0 = blockIdx.x * TLX, by0 = blockIdx.y * TLY;
    const long long bofs = (long long)blockIdx.z * NCHN * HWSZ;
    const short* inb = in + bofs;

    // stage halo tile [by0-1 .. by0+TLY] x [bx0-1 .. bx0+TLX], NHWC
    for (int idx = tid; idx < H2 * W2 * 2; idx += 256) {
        int half = idx & 1, pix = idx >> 1;
        int yy = pix / W2, xx = pix - yy * W2;
        int gy = by0 + yy - 1, gx = bx0 + xx - 1;
        bfrag8 v = {0, 0, 0, 0, 0, 0, 0, 0};
        if ((unsigned)gy < HH && (unsigned)gx < WW)
            v = *(const bfrag8*)(inb + ((long long)gy * WW + gx) * 16 + half * 8);
        *(bfrag8*)(&s_tile[half][yy][xx][0]) = v;
    }

    // A fragments from weights (w layout [co][ci][ky][kx] fp32)
    const int arow = lane & 15;       // cout
    const int grp  = lane >> 4;       // 0..3
    const int half = grp & 1;         // ci block select
    const int cib  = half * 8;
    const int kofb = grp >> 1;        // 0/1 tap offset within kstep
    bfrag8 afrag[5];
#pragma unroll
    for (int s = 0; s < 5; ++s) {
        int koff = 2 * s + kofb;
#pragma unroll
        for (int j = 0; j < 8; ++j) {
            float wv = (koff < 9) ? w[(arow * 16 + cib + j) * 9 + koff] : 0.f;
            afrag[s][j] = f2bf(wv);
        }
    }
    const int c0 = grp * 4;           // C/D cout base
    const float bi0 = bias[c0], bi1 = bias[c0 + 1],
                bi2 = bias[c0 + 2], bi3 = bias[c0 + 3];

    __syncthreads();

    const int pxl = wvid * 16 + (lane & 15);  // local x 0..63
    const int gx = bx0 + pxl;
    short* outb = out + bofs;

    for (int yy = 0; yy < TLY; ++yy) {
        f32x4 acc = { bi0, bi1, bi2, bi3 };
#pragma unroll
        for (int s = 0; s < 5; ++s) {
            int koff = 2 * s + kofb;
            if (koff > 8) koff = 8;           // pad tap: A is zero anyway
            const int dy = koff / 3, dx = koff - dy * 3;   // 0..2
            const bfrag8 bfr = *(const bfrag8*)(&s_tile[half][yy + dy][pxl + dx][0]);
            acc = __builtin_amdgcn_mfma_f32_16x16x32_bf16(afrag[s], bfr, acc, 0, 0, 0);
        }
        short4v st;
#pragma unroll
        for (int i = 0; i < 4; ++i) {
            float r = acc[i];
            st[i] = f2bf(r >= 0.f ? r : 0.01f * r);
        }
        *(short4v*)(outb + ((long long)(by0 + yy) * WW + gx) * 16 + c0) = st;
    }
}

// ---------------------------------------------------------------------------
// Last layer via MFMA: Cin=16 bf16 NHWC, Cout=3 (A rows 3..15 zero).
// C/D mapping puts couts 0..2 in lanes 0..15, regs 0..2 -> those lanes do
// clip + median3 + (xsrc - med) and store 16 consecutive fp32 per wave.
// ---------------------------------------------------------------------------
__global__ __launch_bounds__(256) void k_conv_last_mfma(
    const short* __restrict__ in,
    const float* __restrict__ xsrc, long long xstride,
    float* __restrict__ outp,
    const float* __restrict__ w, const float* __restrict__ bias)
{
    __shared__ short s_tile[2][H2][W2][8];
    const int tid = threadIdx.x;
    const int lane = tid & 63, wvid = tid >> 6;
    const int bx0 = blockIdx.x * TLX, by0 = blockIdx.y * TLY;
    const short* inb = in + (long long)blockIdx.z * NCHN * HWSZ;

    for (int idx = tid; idx < H2 * W2 * 2; idx += 256) {
        int half = idx & 1, pix = idx >> 1;
        int yy = pix / W2, xx = pix - yy * W2;
        int gy = by0 + yy - 1, gx = bx0 + xx - 1;
        bfrag8 v = {0, 0, 0, 0, 0, 0, 0, 0};
        if ((unsigned)gy < HH && (unsigned)gx < WW)
            v = *(const bfrag8*)(inb + ((long long)gy * WW + gx) * 16 + half * 8);
        *(bfrag8*)(&s_tile[half][yy][xx][0]) = v;
    }

    const int arow = lane & 15;
    const int grp  = lane >> 4;
    const int half = grp & 1;
    const int cib  = half * 8;
    const int kofb = grp >> 1;
    bfrag8 afrag[5];
#pragma unroll
    for (int s = 0; s < 5; ++s) {
        int koff = 2 * s + kofb;
#pragma unroll
        for (int j = 0; j < 8; ++j) {
            float wv = (arow < 3 && koff < 9) ? w[(arow * 16 + cib + j) * 9 + koff] : 0.f;
            afrag[s][j] = f2bf(wv);
        }
    }
    // only group 0 (lanes 0..15) holds couts 0..3; bias for rows 0..2
    const float bi0 = (grp == 0) ? bias[0] : 0.f;
    const float bi1 = (grp == 0) ? bias[1] : 0.f;
    const float bi2 = (grp == 0) ? bias[2] : 0.f;

    __syncthreads();

    const int pxl = wvid * 16 + (lane & 15);
    const int gx = bx0 + pxl;
    const float* xb = xsrc + (long long)blockIdx.z * xstride;
    float* ob = outp + (long long)blockIdx.z * HWSZ;

    for (int yy = 0; yy < TLY; ++yy) {
        f32x4 acc = { bi0, bi1, bi2, 0.f };
#pragma unroll
        for (int s = 0; s < 5; ++s) {
            int koff = 2 * s + kofb;
            if (koff > 8) koff = 8;
            const int dy = koff / 3, dx = koff - dy * 3;
            const bfrag8 bfr = *(const bfrag8*)(&s_tile[half][yy + dy][pxl + dx][0]);
            acc = __builtin_amdgcn_mfma_f32_16x16x32_bf16(afrag[s], bfr, acc, 0, 0, 0);
        }
        if (grp == 0) {
            float y0 = fminf(fmaxf(acc[0], -1.f), 1.f);
            float y1 = fminf(fmaxf(acc[1], -1.f), 1.f);
            float y2 = fminf(fmaxf(acc[2], -1.f), 1.f);
            float med = fmaxf(fminf(y0, fmaxf(y1, y2)), fminf(y1, y2));
            const long long pix = (long long)(by0 + yy) * WW + gx;
            ob[pix] = xb[pix] - med;
        }
    }
}

// ---------------------------------------------------------------------------
// Stats over x: sum of squares + per-(b,c) 256-bin histogram
// ---------------------------------------------------------------------------
__global__ __launch_bounds__(256) void k_stats_x(
    const float* __restrict__ x, unsigned* __restrict__ hist, float* __restrict__ sums)
{
    const int p = blockIdx.y;
    const float* src = x + (long long)p * HWSZ;
    __shared__ unsigned h[256];
    h[threadIdx.x] = 0;
    __syncthreads();

    float ss = 0.f;
    for (int i = blockIdx.x * 256 + threadIdx.x; i < HWSZ; i += gridDim.x * 256) {
        float v = src[i];
        ss += v * v;
        if (v >= -1.f && v <= 1.f) {
            int idx = (int)floorf((v + 1.f) * 128.f);
            idx = min(max(idx, 0), 255);
            atomicAdd(&h[idx], 1u);
        }
    }
    __syncthreads();
    if (h[threadIdx.x]) atomicAdd(&hist[p * 256 + threadIdx.x], h[threadIdx.x]);

    float bs = blockSum(ss);
    if (threadIdx.x == 0) atomicAdd(&sums[0], bs);
}

// ---------------------------------------------------------------------------
// Stats over deltas of one plane: delta = v - clampgrad_pred
// ---------------------------------------------------------------------------
__global__ __launch_bounds__(256) void k_stats_delta(
    const float* __restrict__ plane, int c,
    unsigned* __restrict__ hist, float* __restrict__ sums)
{
    const int b = blockIdx.y;
    const float* P = plane + (long long)b * HWSZ;
    const int row = b * 3 + c;
    __shared__ unsigned h[256];
    h[threadIdx.x] = 0;
    __syncthreads();

    float ss = 0.f;
    for (int i = blockIdx.x * 256 + threadIdx.x; i < HWSZ; i += gridDim.x * 256) {
        const int y = i >> 9, x = i & (WW - 1);
        float v = P[i];
        float n  = y ? P[i - WW] : 0.f;
        float wv = x ? P[i - 1] : 0.f;
        float nw = (y && x) ? P[i - WW - 1] : 0.f;
        float pr = n + wv - nw;
        pr = fminf(fmaxf(pr, fminf(n, wv)), fmaxf(n, wv));
        float d = v - pr;
        ss += d * d;
        if (d >= -1.f && d <= 1.f) {
            int idx = (int)floorf((d + 1.f) * 128.f);
            idx = min(max(idx, 0), 255);
            atomicAdd(&h[idx], 1u);
        }
    }
    __syncthreads();
    if (h[threadIdx.x]) atomicAdd(&hist[row * 256 + threadIdx.x], h[threadIdx.x]);

    float bs = blockSum(ss);
    if (threadIdx.x == 0) atomicAdd(&sums[1], bs);
}

// ---------------------------------------------------------------------------
// Finalize: entropies + the 4 output scalars
// ---------------------------------------------------------------------------
__global__ __launch_bounds__(256) void k_finalize(
    const unsigned* __restrict__ hist0, const unsigned* __restrict__ hist1,
    const float* __restrict__ sums, float* __restrict__ out)
{
    float e0 = 0.f, e1 = 0.f;
    for (int i = threadIdx.x; i < 48 * 256; i += 256) {
        float p0 = (float)hist0[i] * (1.0f / HWSZ);
        if (p0 > 0.f) e0 -= p0 * log2f(p0);
        float p1 = (float)hist1[i] * (1.0f / HWSZ);
        if (p1 > 0.f) e1 -= p1 * log2f(p1);
    }
    float t0 = blockSum(e0);
    float t1 = blockSum(e1);
    if (threadIdx.x == 0) {
        const float N = (float)BATCH * 3.f * (float)HWSZ;
        out[0] = 128.f * sqrtf(sums[1] / N);   // loss1 (deltas)
        out[1] = 128.f * sqrtf(sums[0] / N);   // loss0 (x)
        out[2] = t0 * (1.f / (8.f * 48.f));    // invcr0
        out[3] = t1 * (1.f / (8.f * 48.f));    // invcr1
    }
}

// ---------------------------------------------------------------------------
extern "C" void kernel_launch(void* const* d_in, const int* in_sizes, int n_in,
                              void* d_out, int out_size, void* d_ws, size_t ws_size,
                              hipStream_t stream) {
    const float* x = (const float*)d_in[0];
    const float* w[8];
    const float* bs[8];
    for (int i = 0; i < 8; ++i) {
        w[i]  = (const float*)d_in[1 + 2 * i];
        bs[i] = (const float*)d_in[2 + 2 * i];
    }

    // Fixed workspace first (planes + hists + sums ~ 50.4 MB), then
    // activation ping-pong sized adaptively from ws_size (deterministic).
    char* ws = (char*)d_ws;
    size_t o = 0;
    float* rpl = (float*)(ws + o); o += (size_t)BATCH * HWSZ * 4;
    float* gpl = (float*)(ws + o); o += (size_t)BATCH * HWSZ * 4;
    float* bpl = (float*)(ws + o); o += (size_t)BATCH * HWSZ * 4;
    unsigned* hist0 = (unsigned*)(ws + o); o += 48 * 256 * 4;
    unsigned* hist1 = (unsigned*)(ws + o); o += 48 * 256 * 4;
    float* sums = (float*)(ws + o); o += 256;

    const size_t actElems = (size_t)NCHN * HWSZ;        // per batch, shorts
    const size_t perBatchBytes = 2 * actElems * 2;      // A+B buffers
    int chunk = 1;
    if (ws_size > o) {
        size_t c = (ws_size - o) / perBatchBytes;
        chunk = (c < 1) ? 1 : (c > BATCH ? BATCH : (int)c);
    }
    short* actA = (short*)(ws + o);
    short* actB = actA + (size_t)chunk * actElems;

    hipMemsetAsync(hist0, 0, 48 * 256 * 4 * 2 + 256, stream);

    auto predictor = [&](const float* pa, long long sa, const float* pb, long long sb,
                         float* outp, int c) {
        for (int b0 = 0; b0 < BATCH; b0 += chunk) {
            const int zc = (BATCH - b0 < chunk) ? (BATCH - b0) : chunk;
            const dim3 g1(WW / 32, HH / 8, zc);
            const dim3 gm(WW / TLX, HH / TLY, zc);
            k_conv_first<<<g1, 256, 0, stream>>>(pa + (long long)b0 * sa, sa,
                                                 pb + (long long)b0 * sb, sb,
                                                 actA, w[0], bs[0]);
            k_conv16_mfma<<<gm, 256, 0, stream>>>(actA, actB, w[1], bs[1]);
            k_conv16_mfma<<<gm, 256, 0, stream>>>(actB, actA, w[2], bs[2]);
            k_conv16_mfma<<<gm, 256, 0, stream>>>(actA, actB, w[3], bs[3]);
            k_conv16_mfma<<<gm, 256, 0, stream>>>(actB, actA, w[4], bs[4]);
            k_conv16_mfma<<<gm, 256, 0, stream>>>(actA, actB, w[5], bs[5]);
            k_conv16_mfma<<<gm, 256, 0, stream>>>(actB, actA, w[6], bs[6]);
            k_conv_last_mfma<<<gm, 256, 0, stream>>>(
                actA,
                x + (long long)c * HWSZ + (long long)b0 * 3 * HWSZ, 3LL * HWSZ,
                outp + (long long)b0 * HWSZ, w[7], bs[7]);
        }
    };

    // r = x_r - pred(g, b);  g = x_g - pred(r, b);  b = x_b - pred(r, g)
    predictor(x + 1LL * HWSZ, 3LL * HWSZ, x + 2LL * HWSZ, 3LL * HWSZ, rpl, 0);
    predictor(rpl, (long long)HWSZ, x + 2LL * HWSZ, 3LL * HWSZ, gpl, 1);
    predictor(rpl, (long long)HWSZ, gpl, (long long)HWSZ, bpl, 2);

    const dim3 sgrid(64, 48);
    k_stats_x<<<sgrid, 256, 0, stream>>>(x, hist0, sums);
    const dim3 dgrid(64, BATCH);
    k_stats_delta<<<dgrid, 256, 0, stream>>>(rpl, 0, hist1, sums);
    k_stats_delta<<<dgrid, 256, 0, stream>>>(gpl, 1, hist1, sums);
    k_stats_delta<<<dgrid, 256, 0, stream>>>(bpl, 2, hist1, sums);

    k_finalize<<<1, 256, 0, stream>>>(hist0, hist1, sums, (float*)d_out);
}